// Round 1
// baseline (388.657 us; speedup 1.0000x reference)
//
#include <hip/hip_runtime.h>
#include <cstddef>

typedef __attribute__((ext_vector_type(8))) short short8;
typedef __attribute__((ext_vector_type(4))) float f32x4;

__device__ __forceinline__ short f2bf(float f) {
    union { float f; unsigned u; } v; v.f = f;
    unsigned r = v.u + 0x7fffu + ((v.u >> 16) & 1u);
    return (short)(r >> 16);
}

__device__ __forceinline__ short to_bf(float v)  { return f2bf(v); }
__device__ __forceinline__ short to_bf(short v)  { return v; }

// ---------------------------------------------------------------------------
// Tiled transpose: in [R][C] (f32 or bf16) -> out [C][R] bf16. 64x64 tiles.
// ---------------------------------------------------------------------------
template<typename TIN>
__global__ __launch_bounds__(256) void transpose_kernel(
    const TIN* __restrict__ in, short* __restrict__ out,
    int R, int C, long long in_bstride, long long out_bstride)
{
    __shared__ short tile[64][68];
    in  += (size_t)blockIdx.z * in_bstride;
    out += (size_t)blockIdx.z * out_bstride;
    int r0 = blockIdx.y * 64, c0 = blockIdx.x * 64;
    int t = threadIdx.x;
    int tr = t >> 6, tc = t & 63;
#pragma unroll
    for (int i = 0; i < 16; ++i) {
        int r = i * 4 + tr;
        tile[r][tc] = to_bf(in[(size_t)(r0 + r) * C + (c0 + tc)]);
    }
    __syncthreads();
#pragma unroll
    for (int i = 0; i < 16; ++i) {
        int r = i * 4 + tr;   // output row within tile = input col
        out[(size_t)(c0 + r) * R + (r0 + tc)] = tile[tc][r];
    }
}

// ---------------------------------------------------------------------------
// Generic bf16 MFMA GEMM: C[M][N] = A[M][K] * BT[N][K]^T
// AF32: A is f32 (convert while staging) else bf16.
// EPI 0: store bf16 row-major
// EPI 2: +bias, exact GELU, store bf16
// EPI 3: +bias, +resid (f32), store f32
// Tile 128x128, BK=32, 4 waves (64x64 each).
// ---------------------------------------------------------------------------
template<int AF32, int EPI>
__global__ __launch_bounds__(256) void gemm_kernel(
    const void* __restrict__ Av, const short* __restrict__ BT,
    void* __restrict__ outv, const float* __restrict__ bias,
    const float* __restrict__ resid, int M, int N, int K)
{
    __shared__ short As[128][32];
    __shared__ short Bs[128][32];
    const int nb = N >> 7;
    const int m0 = (blockIdx.x / nb) << 7;
    const int n0 = (blockIdx.x % nb) << 7;
    const int t = threadIdx.x;
    const int lane = t & 63, w = t >> 6;
    const int wm = w >> 1, wn = w & 1;
    const int lo = lane & 15, hi = lane >> 4;

    const f32x4 zero = {0.f, 0.f, 0.f, 0.f};
    f32x4 acc[4][4];
#pragma unroll
    for (int i = 0; i < 4; ++i)
#pragma unroll
        for (int j = 0; j < 4; ++j) acc[i][j] = zero;

    const int rdoff = (hi ^ ((lo >> 1) & 3)) * 8;   // swizzled read chunk

    for (int kt = 0; kt < K; kt += 32) {
        if (AF32) {
            const float* A = (const float*)Av;
#pragma unroll
            for (int i = 0; i < 2; ++i) {
                int c = i * 256 + t;
                int row = c >> 2, ch = c & 3;
                const float* src = A + (size_t)(m0 + row) * K + kt + ch * 8;
                f32x4 u0 = *(const f32x4*)src;
                f32x4 u1 = *(const f32x4*)(src + 4);
                short8 dv;
                dv[0] = f2bf(u0[0]); dv[1] = f2bf(u0[1]);
                dv[2] = f2bf(u0[2]); dv[3] = f2bf(u0[3]);
                dv[4] = f2bf(u1[0]); dv[5] = f2bf(u1[1]);
                dv[6] = f2bf(u1[2]); dv[7] = f2bf(u1[3]);
                int chs = ch ^ ((row >> 1) & 3);
                *(short8*)&As[row][chs * 8] = dv;
            }
        } else {
            const short* A = (const short*)Av;
#pragma unroll
            for (int i = 0; i < 2; ++i) {
                int c = i * 256 + t;
                int row = c >> 2, ch = c & 3;
                short8 dv = *(const short8*)(A + (size_t)(m0 + row) * K + kt + ch * 8);
                int chs = ch ^ ((row >> 1) & 3);
                *(short8*)&As[row][chs * 8] = dv;
            }
        }
#pragma unroll
        for (int i = 0; i < 2; ++i) {
            int c = i * 256 + t;
            int row = c >> 2, ch = c & 3;
            short8 dv = *(const short8*)(BT + (size_t)(n0 + row) * K + kt + ch * 8);
            int chs = ch ^ ((row >> 1) & 3);
            *(short8*)&Bs[row][chs * 8] = dv;
        }
        __syncthreads();

        short8 af[4], bf[4];
#pragma unroll
        for (int mi = 0; mi < 4; ++mi)
            af[mi] = *(const short8*)&As[wm * 64 + mi * 16 + lo][rdoff];
#pragma unroll
        for (int ni = 0; ni < 4; ++ni)
            bf[ni] = *(const short8*)&Bs[wn * 64 + ni * 16 + lo][rdoff];
#pragma unroll
        for (int mi = 0; mi < 4; ++mi)
#pragma unroll
            for (int ni = 0; ni < 4; ++ni)
                acc[mi][ni] = __builtin_amdgcn_mfma_f32_16x16x32_bf16(
                    af[mi], bf[ni], acc[mi][ni], 0, 0, 0);
        __syncthreads();
    }

#pragma unroll
    for (int mi = 0; mi < 4; ++mi) {
#pragma unroll
        for (int ni = 0; ni < 4; ++ni) {
#pragma unroll
            for (int r = 0; r < 4; ++r) {
                int row = m0 + wm * 64 + mi * 16 + hi * 4 + r;
                int col = n0 + wn * 64 + ni * 16 + lo;
                size_t idx = (size_t)row * N + col;
                float v = acc[mi][ni][r];
                if (EPI == 0) {
                    ((short*)outv)[idx] = f2bf(v);
                } else if (EPI == 2) {
                    v += bias[col];
                    v = 0.5f * v * (1.0f + erff(v * 0.70710678118654752f));
                    ((short*)outv)[idx] = f2bf(v);
                } else {
                    v += bias[col] + resid[idx];
                    ((float*)outv)[idx] = v;
                }
            }
        }
    }
}

// ---------------------------------------------------------------------------
// Flash attention + residual.
// grid 256: bid = qb*8 + n  (batch = bid&7 -> XCD affinity for K/V reuse)
// block 512 (8 waves): wave w: row-group rg=w>>1 (16 q-rows), col-half ch=w&1
// (256 of 512 v-dims). QK^T duplicated across the pair; online softmax f32.
// Writes xres = x + attn @ v (f32) to d_out.
// ---------------------------------------------------------------------------
__global__ __launch_bounds__(512) void flash_kernel(
    const float* __restrict__ x,   // [8][2048][512]
    const short* __restrict__ qb,  // [8*2048][128] bf16
    const short* __restrict__ kb,  // [8*2048][128] bf16
    const short* __restrict__ vT,  // [8][512][2048] bf16
    float* __restrict__ xres)      // [8][2048][512]
{
    __shared__ short ks[32][128];      // K-tile, swizzle chunk ^= (row&7)
    __shared__ short vs[512][32];      // V^T-tile, swizzle chunk ^= ((row>>1)&3)
    __shared__ short ps[8][16][32];    // per-wave P, swizzle chunk ^= ((row>>1)&3)

    const int bid = blockIdx.x;
    const int n = bid & 7;
    const int q0 = (bid >> 3) << 6;
    const int t = threadIdx.x, lane = t & 63, w = t >> 6;
    const int rg = w >> 1, chh = w & 1;
    const int lo = lane & 15, hi = lane >> 4;
    const float scale = 0.08838834764831845f;  // 1/sqrt(128)

    // Q fragments, kept in registers
    short8 qf[4];
    {
        const short* qrow = qb + ((size_t)(n * 2048 + q0 + rg * 16 + lo) << 7);
#pragma unroll
        for (int kf = 0; kf < 4; ++kf)
            qf[kf] = *(const short8*)(qrow + kf * 32 + hi * 8);
    }

    const f32x4 zero = {0.f, 0.f, 0.f, 0.f};
    f32x4 o[16];
#pragma unroll
    for (int i = 0; i < 16; ++i) o[i] = zero;
    float m_run[4], l_run[4];
#pragma unroll
    for (int r = 0; r < 4; ++r) { m_run[r] = -1e30f; l_run[r] = 0.f; }

    for (int kt = 0; kt < 2048; kt += 32) {
        // stage K-tile [32][128]
        {
            int row = t >> 4, ch = t & 15;
            short8 dv = *(const short8*)(kb + ((size_t)(n * 2048 + kt + row) << 7) + ch * 8);
            int chs = ch ^ (row & 7);
            *(short8*)&ks[row][chs * 8] = dv;
        }
        // stage V^T-tile [512][32]
#pragma unroll
        for (int i = 0; i < 4; ++i) {
            int cid = i * 512 + t;
            int row = cid >> 2, ch = cid & 3;
            short8 dv = *(const short8*)(vT + ((size_t)(n * 512 + row) << 11) + kt + ch * 8);
            int chs = ch ^ ((row >> 1) & 3);
            *(short8*)&vs[row][chs * 8] = dv;
        }
        __syncthreads();

        // S = Q K^T  (rows: hi*4+r of 16; cols: nb2*16+lo of 32 keys)
        f32x4 s[2];
#pragma unroll
        for (int nb2 = 0; nb2 < 2; ++nb2) {
            f32x4 a = zero;
            int row = nb2 * 16 + lo;
#pragma unroll
            for (int kf = 0; kf < 4; ++kf) {
                int chs = (kf * 4 + hi) ^ (row & 7);
                short8 kfrag = *(const short8*)&ks[row][chs * 8];
                a = __builtin_amdgcn_mfma_f32_16x16x32_bf16(qf[kf], kfrag, a, 0, 0, 0);
            }
            s[nb2] = a;
        }

        // online softmax
        float alpha[4];
#pragma unroll
        for (int r = 0; r < 4; ++r) {
            float s0 = s[0][r] * scale, s1 = s[1][r] * scale;
            float m = fmaxf(s0, s1);
            m = fmaxf(m, __shfl_xor(m, 1));
            m = fmaxf(m, __shfl_xor(m, 2));
            m = fmaxf(m, __shfl_xor(m, 4));
            m = fmaxf(m, __shfl_xor(m, 8));
            float m_new = fmaxf(m_run[r], m);
            alpha[r] = __expf(m_run[r] - m_new);
            m_run[r] = m_new;
            float p0 = __expf(s0 - m_new);
            float p1 = __expf(s1 - m_new);
            s[0][r] = p0; s[1][r] = p1;
            float sum = p0 + p1;
            sum += __shfl_xor(sum, 1);
            sum += __shfl_xor(sum, 2);
            sum += __shfl_xor(sum, 4);
            sum += __shfl_xor(sum, 8);
            l_run[r] = l_run[r] * alpha[r] + sum;
        }
#pragma unroll
        for (int cb = 0; cb < 16; ++cb)
#pragma unroll
            for (int r = 0; r < 4; ++r) o[cb][r] *= alpha[r];

        // P -> LDS (bf16), then read back as A-fragment
#pragma unroll
        for (int nb2 = 0; nb2 < 2; ++nb2) {
#pragma unroll
            for (int r = 0; r < 4; ++r) {
                int prow = hi * 4 + r;
                int col = nb2 * 16 + lo;
                int chs = (col >> 3) ^ ((prow >> 1) & 3);
                ps[w][prow][chs * 8 + (col & 7)] = f2bf(s[nb2][r]);
            }
        }
        short8 pa = *(const short8*)&ps[w][lo][(hi ^ ((lo >> 1) & 3)) * 8];

        // O += P V
#pragma unroll
        for (int cb = 0; cb < 16; ++cb) {
            int row = chh * 256 + cb * 16 + lo;
            int chs = hi ^ ((row >> 1) & 3);
            short8 vfrag = *(const short8*)&vs[row][chs * 8];
            o[cb] = __builtin_amdgcn_mfma_f32_16x16x32_bf16(pa, vfrag, o[cb], 0, 0, 0);
        }
        __syncthreads();
    }

    float inv[4];
#pragma unroll
    for (int r = 0; r < 4; ++r) inv[r] = 1.0f / l_run[r];
#pragma unroll
    for (int cb = 0; cb < 16; ++cb) {
#pragma unroll
        for (int r = 0; r < 4; ++r) {
            int row = q0 + rg * 16 + hi * 4 + r;
            int col = chh * 256 + cb * 16 + lo;
            size_t idx = ((size_t)(n * 2048 + row) << 9) + col;
            xres[idx] = x[idx] + o[cb][r] * inv[r];
        }
    }
}

// ---------------------------------------------------------------------------
// LayerNorm: xres f32 [16384][512] -> hb bf16. One wave per row.
// ---------------------------------------------------------------------------
__global__ __launch_bounds__(256) void ln_kernel(
    const float* __restrict__ xr, const float* __restrict__ gamma,
    const float* __restrict__ beta, short* __restrict__ hb)
{
    int row = (blockIdx.x << 2) + (threadIdx.x >> 6);
    int lane = threadIdx.x & 63;
    const float* p = xr + ((size_t)row << 9) + lane * 8;
    f32x4 a = *(const f32x4*)p;
    f32x4 b = *(const f32x4*)(p + 4);
    float s = a[0] + a[1] + a[2] + a[3] + b[0] + b[1] + b[2] + b[3];
#pragma unroll
    for (int m = 1; m < 64; m <<= 1) s += __shfl_xor(s, m);
    float mu = s * (1.0f / 512.0f);
    float q = 0.f;
#pragma unroll
    for (int j = 0; j < 4; ++j) { float d = a[j] - mu; q += d * d; }
#pragma unroll
    for (int j = 0; j < 4; ++j) { float d = b[j] - mu; q += d * d; }
#pragma unroll
    for (int m = 1; m < 64; m <<= 1) q += __shfl_xor(q, m);
    float rs = rsqrtf(q * (1.0f / 512.0f) + 1e-5f);
    f32x4 g0 = *(const f32x4*)(gamma + lane * 8);
    f32x4 g1 = *(const f32x4*)(gamma + lane * 8 + 4);
    f32x4 e0 = *(const f32x4*)(beta + lane * 8);
    f32x4 e1 = *(const f32x4*)(beta + lane * 8 + 4);
    short8 ov;
#pragma unroll
    for (int j = 0; j < 4; ++j) ov[j]     = f2bf((a[j] - mu) * rs * g0[j] + e0[j]);
#pragma unroll
    for (int j = 0; j < 4; ++j) ov[4 + j] = f2bf((b[j] - mu) * rs * g1[j] + e1[j]);
    *(short8*)(hb + ((size_t)row << 9) + lane * 8) = ov;
}

// ---------------------------------------------------------------------------
extern "C" void kernel_launch(void* const* d_in, const int* in_sizes, int n_in,
                              void* d_out, int out_size, void* d_ws, size_t ws_size,
                              hipStream_t stream)
{
    const float* x     = (const float*)d_in[0];
    const float* y     = (const float*)d_in[1];
    const float* Wq    = (const float*)d_in[2];
    const float* Wk    = (const float*)d_in[3];
    const float* Wv    = (const float*)d_in[4];
    const float* gamma = (const float*)d_in[5];
    const float* beta  = (const float*)d_in[6];
    const float* W1    = (const float*)d_in[7];
    const float* b1    = (const float*)d_in[8];
    const float* W2    = (const float*)d_in[9];
    const float* b2    = (const float*)d_in[10];
    float* out = (float*)d_out;

    char* ws = (char*)d_ws;
    size_t off = 0;
    auto alloc = [&](size_t bytes) -> void* {
        void* p = ws + off;
        off += (bytes + 255) & ~(size_t)255;
        return p;
    };
    short* WqT = (short*)alloc((size_t)128 * 512 * 2);
    short* WkT = (short*)alloc((size_t)128 * 512 * 2);
    short* WvT = (short*)alloc((size_t)512 * 512 * 2);
    short* W1T = (short*)alloc((size_t)1024 * 512 * 2);
    short* W2T = (short*)alloc((size_t)512 * 1024 * 2);
    short* qb  = (short*)alloc((size_t)16384 * 128 * 2);
    short* kbf = (short*)alloc((size_t)16384 * 128 * 2);
    short* vb  = (short*)alloc((size_t)16384 * 512 * 2);
    short* vT  = (short*)alloc((size_t)16384 * 512 * 2);
    short* hb  = (short*)alloc((size_t)16384 * 512 * 2);
    short* gb  = (short*)alloc((size_t)16384 * 1024 * 2);

    // weight transposes (f32 [K][N] -> bf16 [N][K])
    transpose_kernel<float><<<dim3(2, 8, 1),  256, 0, stream>>>(Wq, WqT, 512, 128, 0, 0);
    transpose_kernel<float><<<dim3(2, 8, 1),  256, 0, stream>>>(Wk, WkT, 512, 128, 0, 0);
    transpose_kernel<float><<<dim3(8, 8, 1),  256, 0, stream>>>(Wv, WvT, 512, 512, 0, 0);
    transpose_kernel<float><<<dim3(16, 8, 1), 256, 0, stream>>>(W1, W1T, 512, 1024, 0, 0);
    transpose_kernel<float><<<dim3(8, 16, 1), 256, 0, stream>>>(W2, W2T, 1024, 512, 0, 0);

    // projections: q = x Wq, k = y Wk, v = y Wv
    gemm_kernel<1, 0><<<dim3(128), 256, 0, stream>>>(x, WqT, qb,  nullptr, nullptr, 16384, 128, 512);
    gemm_kernel<1, 0><<<dim3(128), 256, 0, stream>>>(y, WkT, kbf, nullptr, nullptr, 16384, 128, 512);
    gemm_kernel<1, 0><<<dim3(512), 256, 0, stream>>>(y, WvT, vb,  nullptr, nullptr, 16384, 512, 512);

    // v -> v^T per batch: [2048][512] -> [512][2048]
    transpose_kernel<short><<<dim3(8, 32, 8), 256, 0, stream>>>(
        vb, vT, 2048, 512, (long long)2048 * 512, (long long)512 * 2048);

    // attention + residual -> d_out (x_res)
    flash_kernel<<<dim3(256), 512, 0, stream>>>(x, qb, kbf, vT, out);

    // layernorm -> hb
    ln_kernel<<<dim3(4096), 256, 0, stream>>>(out, gamma, beta, hb);

    // MLP
    gemm_kernel<0, 2><<<dim3(1024), 256, 0, stream>>>(hb, W1T, gb, b1, nullptr, 16384, 1024, 512);
    gemm_kernel<0, 3><<<dim3(512),  256, 0, stream>>>(gb, W2T, out, b2, out,    16384, 512, 1024);

    (void)in_sizes; (void)n_in; (void)out_size; (void)ws_size;
}

// Round 2
// 276.526 us; speedup vs baseline: 1.4055x; 1.4055x over previous
//
#include <hip/hip_runtime.h>
#include <cstddef>

typedef __attribute__((ext_vector_type(8))) short short8;
typedef __attribute__((ext_vector_type(4))) float f32x4;
typedef __attribute__((ext_vector_type(16))) float f32x16;

__device__ __forceinline__ short f2bf(float f) {
    union { float f; unsigned u; } v; v.f = f;
    unsigned r = v.u + 0x7fffu + ((v.u >> 16) & 1u);
    return (short)(r >> 16);
}

__device__ __forceinline__ short to_bf(float v)  { return f2bf(v); }
__device__ __forceinline__ short to_bf(short v)  { return v; }

// ---------------------------------------------------------------------------
// Tiled transpose: in [R][C] (f32 or bf16) -> out [C][R] bf16. 64x64 tiles.
// ---------------------------------------------------------------------------
template<typename TIN>
__global__ __launch_bounds__(256) void transpose_kernel(
    const TIN* __restrict__ in, short* __restrict__ out,
    int R, int C, long long in_bstride, long long out_bstride)
{
    __shared__ short tile[64][68];
    in  += (size_t)blockIdx.z * in_bstride;
    out += (size_t)blockIdx.z * out_bstride;
    int r0 = blockIdx.y * 64, c0 = blockIdx.x * 64;
    int t = threadIdx.x;
    int tr = t >> 6, tc = t & 63;
#pragma unroll
    for (int i = 0; i < 16; ++i) {
        int r = i * 4 + tr;
        tile[r][tc] = to_bf(in[(size_t)(r0 + r) * C + (c0 + tc)]);
    }
    __syncthreads();
#pragma unroll
    for (int i = 0; i < 16; ++i) {
        int r = i * 4 + tr;   // output row within tile = input col
        out[(size_t)(c0 + r) * R + (r0 + tc)] = tile[tc][r];
    }
}

// ---------------------------------------------------------------------------
// Generic bf16 MFMA GEMM: C[M][N] = A[M][K] * BT[N][K]^T
// Tile 128x128, BK=32, 4 waves (64x64 each).
// ---------------------------------------------------------------------------
template<int AF32, int EPI>
__global__ __launch_bounds__(256) void gemm_kernel(
    const void* __restrict__ Av, const short* __restrict__ BT,
    void* __restrict__ outv, const float* __restrict__ bias,
    const float* __restrict__ resid, int M, int N, int K)
{
    __shared__ short As[128][32];
    __shared__ short Bs[128][32];
    const int nb = N >> 7;
    const int m0 = (blockIdx.x / nb) << 7;
    const int n0 = (blockIdx.x % nb) << 7;
    const int t = threadIdx.x;
    const int lane = t & 63, w = t >> 6;
    const int wm = w >> 1, wn = w & 1;
    const int lo = lane & 15, hi = lane >> 4;

    const f32x4 zero = {0.f, 0.f, 0.f, 0.f};
    f32x4 acc[4][4];
#pragma unroll
    for (int i = 0; i < 4; ++i)
#pragma unroll
        for (int j = 0; j < 4; ++j) acc[i][j] = zero;

    const int rdoff = (hi ^ ((lo >> 1) & 3)) * 8;   // swizzled read chunk

    for (int kt = 0; kt < K; kt += 32) {
        if (AF32) {
            const float* A = (const float*)Av;
#pragma unroll
            for (int i = 0; i < 2; ++i) {
                int c = i * 256 + t;
                int row = c >> 2, ch = c & 3;
                const float* src = A + (size_t)(m0 + row) * K + kt + ch * 8;
                f32x4 u0 = *(const f32x4*)src;
                f32x4 u1 = *(const f32x4*)(src + 4);
                short8 dv;
                dv[0] = f2bf(u0[0]); dv[1] = f2bf(u0[1]);
                dv[2] = f2bf(u0[2]); dv[3] = f2bf(u0[3]);
                dv[4] = f2bf(u1[0]); dv[5] = f2bf(u1[1]);
                dv[6] = f2bf(u1[2]); dv[7] = f2bf(u1[3]);
                int chs = ch ^ ((row >> 1) & 3);
                *(short8*)&As[row][chs * 8] = dv;
            }
        } else {
            const short* A = (const short*)Av;
#pragma unroll
            for (int i = 0; i < 2; ++i) {
                int c = i * 256 + t;
                int row = c >> 2, ch = c & 3;
                short8 dv = *(const short8*)(A + (size_t)(m0 + row) * K + kt + ch * 8);
                int chs = ch ^ ((row >> 1) & 3);
                *(short8*)&As[row][chs * 8] = dv;
            }
        }
#pragma unroll
        for (int i = 0; i < 2; ++i) {
            int c = i * 256 + t;
            int row = c >> 2, ch = c & 3;
            short8 dv = *(const short8*)(BT + (size_t)(n0 + row) * K + kt + ch * 8);
            int chs = ch ^ ((row >> 1) & 3);
            *(short8*)&Bs[row][chs * 8] = dv;
        }
        __syncthreads();

        short8 af[4], bf[4];
#pragma unroll
        for (int mi = 0; mi < 4; ++mi)
            af[mi] = *(const short8*)&As[wm * 64 + mi * 16 + lo][rdoff];
#pragma unroll
        for (int ni = 0; ni < 4; ++ni)
            bf[ni] = *(const short8*)&Bs[wn * 64 + ni * 16 + lo][rdoff];
#pragma unroll
        for (int mi = 0; mi < 4; ++mi)
#pragma unroll
            for (int ni = 0; ni < 4; ++ni)
                acc[mi][ni] = __builtin_amdgcn_mfma_f32_16x16x32_bf16(
                    af[mi], bf[ni], acc[mi][ni], 0, 0, 0);
        __syncthreads();
    }

#pragma unroll
    for (int mi = 0; mi < 4; ++mi) {
#pragma unroll
        for (int ni = 0; ni < 4; ++ni) {
#pragma unroll
            for (int r = 0; r < 4; ++r) {
                int row = m0 + wm * 64 + mi * 16 + hi * 4 + r;
                int col = n0 + wn * 64 + ni * 16 + lo;
                size_t idx = (size_t)row * N + col;
                float v = acc[mi][ni][r];
                if (EPI == 0) {
                    ((short*)outv)[idx] = f2bf(v);
                } else if (EPI == 2) {
                    v += bias[col];
                    v = 0.5f * v * (1.0f + erff(v * 0.70710678118654752f));
                    ((short*)outv)[idx] = f2bf(v);
                } else {
                    v += bias[col] + resid[idx];
                    ((float*)outv)[idx] = v;
                }
            }
        }
    }
}

// ---------------------------------------------------------------------------
// Flash attention + residual, 32x32 MFMA, swapped QK^T, in-register softmax.
// grid 256: bid = qtile*8 + batch (batch = bid&7 -> XCD affinity for K/V L2).
// block 512 (8 waves): wave w: rowgroup rg=w>>2 (32 q-rows), quarter qt=w&3
// (128 of 512 v-dims). KVBLK=64, T14 reg-staged K/V, XOR-swizzled LDS.
// Swapped QK^T: S = mfma(K, Q) -> lane owns one q-row (col=lane&31) ->
// row softmax is in-lane (+1 shfl_xor(32)); P assembled in-register via
// v_cvt_pk_bf16_f32 + shfl_xor(32); defer-max rescale (THR=8 exp-units).
// ---------------------------------------------------------------------------
__global__ __launch_bounds__(512) void flash_kernel(
    const float* __restrict__ x,   // [8][2048][512] f32
    const short* __restrict__ qb,  // [8*2048][128] bf16
    const short* __restrict__ kb,  // [8*2048][128] bf16
    const short* __restrict__ vT,  // [8][512][2048] bf16
    float* __restrict__ xres)      // [8][2048][512] f32
{
    __shared__ short ks[64][128];   // K tile, 16B-chunk swizzle: ch ^= (row&7)
    __shared__ short vs[512][64];   // V^T tile, ch ^= (row&7)

    const int bid = blockIdx.x;
    const int n = bid & 7;
    const int q0 = (bid >> 3) << 6;
    const int t = threadIdx.x, lane = t & 63, w = t >> 6;
    const int rg = w >> 2, qt = w & 3;
    const int lo5 = lane & 31, hi2 = lane >> 5;
    const float scale = 0.08838834764831845f;   // 1/sqrt(128)
    const float THR = 90.5f;                    // 8/scale

    // Q B-fragments (b[k=d][col=qrow]): lane holds Q[qrow=lo5][d=s*16+hi2*8+j]
    short8 qf[8];
    {
        const short* qrow = qb + ((size_t)(n * 2048 + q0 + rg * 32 + lo5) << 7);
#pragma unroll
        for (int s = 0; s < 8; ++s)
            qf[s] = *(const short8*)(qrow + s * 16 + hi2 * 8);
    }

    f32x16 o[4] = {};                 // o[nb]: 32 qrows x 32 vdims each
    float m_run = -1e30f, l_run = 0.f;

    short8 kreg[2], vreg[8];
    // prologue: stage tile 0
#pragma unroll
    for (int i = 0; i < 2; ++i) {
        int c = i * 512 + t, row = c >> 4, ch = c & 15;
        kreg[i] = *(const short8*)(kb + ((size_t)(n * 2048 + row) << 7) + ch * 8);
    }
#pragma unroll
    for (int i = 0; i < 8; ++i) {
        int c = i * 512 + t, row = c >> 3, ch = c & 7;
        vreg[i] = *(const short8*)(vT + ((size_t)(n * 512 + row) << 11) + ch * 8);
    }
#pragma unroll
    for (int i = 0; i < 2; ++i) {
        int c = i * 512 + t, row = c >> 4, ch = c & 15;
        *(short8*)&ks[row][(ch ^ (row & 7)) * 8] = kreg[i];
    }
#pragma unroll
    for (int i = 0; i < 8; ++i) {
        int c = i * 512 + t, row = c >> 3, ch = c & 7;
        *(short8*)&vs[row][(ch ^ (row & 7)) * 8] = vreg[i];
    }
    __syncthreads();

    for (int kt = 0; kt < 2048; kt += 64) {
        const bool hn = (kt + 64) < 2048;
        // T14: issue next tile's global loads before compute
        if (hn) {
            int ktn = kt + 64;
#pragma unroll
            for (int i = 0; i < 2; ++i) {
                int c = i * 512 + t, row = c >> 4, ch = c & 15;
                kreg[i] = *(const short8*)(kb + ((size_t)(n * 2048 + ktn + row) << 7) + ch * 8);
            }
#pragma unroll
            for (int i = 0; i < 8; ++i) {
                int c = i * 512 + t, row = c >> 3, ch = c & 7;
                vreg[i] = *(const short8*)(vT + ((size_t)(n * 512 + row) << 11) + ktn + ch * 8);
            }
        }

        // QK^T swapped: sacc[m] = S[key = m*32 + reg-pattern][qrow = lo5]
        f32x16 sacc[2] = {};
#pragma unroll
        for (int m = 0; m < 2; ++m) {
            int krow = m * 32 + lo5;
            int sw = krow & 7;
#pragma unroll
            for (int s = 0; s < 8; ++s) {
                short8 kf = *(const short8*)&ks[krow][((s * 2 + hi2) ^ sw) * 8];
                sacc[m] = __builtin_amdgcn_mfma_f32_32x32x16_bf16(kf, qf[s], sacc[m], 0, 0, 0);
            }
        }

        // in-lane softmax (lane owns qrow lo5; 32 of 64 keys, other half at hi2^1)
        float mt = sacc[0][0];
#pragma unroll
        for (int r = 1; r < 16; ++r) mt = fmaxf(mt, sacc[0][r]);
#pragma unroll
        for (int r = 0; r < 16; ++r) mt = fmaxf(mt, sacc[1][r]);
        mt = fmaxf(mt, __shfl_xor(mt, 32));

        if (!__all(mt - m_run <= THR)) {
            float m_new = fmaxf(m_run, mt);
            float alpha = __expf((m_run - m_new) * scale);
            l_run *= alpha;
#pragma unroll
            for (int r = 0; r < 16; ++r) {
                int qr = (r & 3) + 8 * (r >> 2) + 4 * hi2;
                float ar = __shfl(alpha, qr);
#pragma unroll
                for (int nb2 = 0; nb2 < 4; ++nb2) o[nb2][r] *= ar;
            }
            m_run = m_new;
        }
        float msc = m_run * scale;
        float lsum = 0.f;
#pragma unroll
        for (int m = 0; m < 2; ++m)
#pragma unroll
            for (int r = 0; r < 16; ++r) {
                float p = __expf(fmaf(sacc[m][r], scale, -msc));
                sacc[m][r] = p;
                lsum += p;
            }
        l_run += lsum;

        // P -> bf16 A-fragments fully in-register (cvt_pk + shfl_xor(32))
        short8 pa[4];
#pragma unroll
        for (int m = 0; m < 2; ++m) {
            int wq[8], sx[8];
#pragma unroll
            for (int q2 = 0; q2 < 8; ++q2) {
                int a;
                asm("v_cvt_pk_bf16_f32 %0, %1, %2"
                    : "=v"(a) : "v"(sacc[m][2 * q2]), "v"(sacc[m][2 * q2 + 1]));
                wq[q2] = a;
            }
#pragma unroll
            for (int q2 = 0; q2 < 8; ++q2) sx[q2] = __shfl_xor(wq[q2], 32);
            union { int i[4]; short8 v; } u0, u1;
            u0.i[0] = hi2 ? sx[2] : wq[0];
            u0.i[1] = hi2 ? sx[3] : wq[1];
            u0.i[2] = hi2 ? wq[2] : sx[0];
            u0.i[3] = hi2 ? wq[3] : sx[1];
            u1.i[0] = hi2 ? sx[6] : wq[4];
            u1.i[1] = hi2 ? sx[7] : wq[5];
            u1.i[2] = hi2 ? wq[6] : sx[4];
            u1.i[3] = hi2 ? wq[7] : sx[5];
            pa[2 * m] = u0.v;
            pa[2 * m + 1] = u1.v;
        }

        // O += P V : o[nb][qrow][vd], A = pa[kstep], B = V-frag from vs
#pragma unroll
        for (int ks2 = 0; ks2 < 4; ++ks2) {
#pragma unroll
            for (int nb2 = 0; nb2 < 4; ++nb2) {
                int row = qt * 128 + nb2 * 32 + lo5;
                short8 vf = *(const short8*)&vs[row][((ks2 * 2 + hi2) ^ (row & 7)) * 8];
                o[nb2] = __builtin_amdgcn_mfma_f32_32x32x16_bf16(pa[ks2], vf, o[nb2], 0, 0, 0);
            }
        }

        if (hn) {
            __syncthreads();   // all waves done reading tile t
#pragma unroll
            for (int i = 0; i < 2; ++i) {
                int c = i * 512 + t, row = c >> 4, ch = c & 15;
                *(short8*)&ks[row][(ch ^ (row & 7)) * 8] = kreg[i];
            }
#pragma unroll
            for (int i = 0; i < 8; ++i) {
                int c = i * 512 + t, row = c >> 3, ch = c & 7;
                *(short8*)&vs[row][(ch ^ (row & 7)) * 8] = vreg[i];
            }
            __syncthreads();   // tile t+1 visible
        }
    }

    // epilogue: normalize + residual
    float l_tot = l_run + __shfl_xor(l_run, 32);
    float inv = 1.0f / l_tot;
#pragma unroll
    for (int r = 0; r < 16; ++r) {
        int qr = (r & 3) + 8 * (r >> 2) + 4 * hi2;
        float ir = __shfl(inv, qr);
        int row = q0 + rg * 32 + qr;
        size_t base = ((size_t)(n * 2048 + row) << 9) + qt * 128 + lo5;
#pragma unroll
        for (int nb2 = 0; nb2 < 4; ++nb2) {
            size_t idx = base + nb2 * 32;
            xres[idx] = x[idx] + o[nb2][r] * ir;
        }
    }
}

// ---------------------------------------------------------------------------
// LayerNorm: xres f32 [16384][512] -> hb bf16. One wave per row.
// ---------------------------------------------------------------------------
__global__ __launch_bounds__(256) void ln_kernel(
    const float* __restrict__ xr, const float* __restrict__ gamma,
    const float* __restrict__ beta, short* __restrict__ hb)
{
    int row = (blockIdx.x << 2) + (threadIdx.x >> 6);
    int lane = threadIdx.x & 63;
    const float* p = xr + ((size_t)row << 9) + lane * 8;
    f32x4 a = *(const f32x4*)p;
    f32x4 b = *(const f32x4*)(p + 4);
    float s = a[0] + a[1] + a[2] + a[3] + b[0] + b[1] + b[2] + b[3];
#pragma unroll
    for (int m = 1; m < 64; m <<= 1) s += __shfl_xor(s, m);
    float mu = s * (1.0f / 512.0f);
    float q = 0.f;
#pragma unroll
    for (int j = 0; j < 4; ++j) { float d = a[j] - mu; q += d * d; }
#pragma unroll
    for (int j = 0; j < 4; ++j) { float d = b[j] - mu; q += d * d; }
#pragma unroll
    for (int m = 1; m < 64; m <<= 1) q += __shfl_xor(q, m);
    float rs = rsqrtf(q * (1.0f / 512.0f) + 1e-5f);
    f32x4 g0 = *(const f32x4*)(gamma + lane * 8);
    f32x4 g1 = *(const f32x4*)(gamma + lane * 8 + 4);
    f32x4 e0 = *(const f32x4*)(beta + lane * 8);
    f32x4 e1 = *(const f32x4*)(beta + lane * 8 + 4);
    short8 ov;
#pragma unroll
    for (int j = 0; j < 4; ++j) ov[j]     = f2bf((a[j] - mu) * rs * g0[j] + e0[j]);
#pragma unroll
    for (int j = 0; j < 4; ++j) ov[4 + j] = f2bf((b[j] - mu) * rs * g1[j] + e1[j]);
    *(short8*)(hb + ((size_t)row << 9) + lane * 8) = ov;
}

// ---------------------------------------------------------------------------
extern "C" void kernel_launch(void* const* d_in, const int* in_sizes, int n_in,
                              void* d_out, int out_size, void* d_ws, size_t ws_size,
                              hipStream_t stream)
{
    const float* x     = (const float*)d_in[0];
    const float* y     = (const float*)d_in[1];
    const float* Wq    = (const float*)d_in[2];
    const float* Wk    = (const float*)d_in[3];
    const float* Wv    = (const float*)d_in[4];
    const float* gamma = (const float*)d_in[5];
    const float* beta  = (const float*)d_in[6];
    const float* W1    = (const float*)d_in[7];
    const float* b1    = (const float*)d_in[8];
    const float* W2    = (const float*)d_in[9];
    const float* b2    = (const float*)d_in[10];
    float* out = (float*)d_out;

    char* ws = (char*)d_ws;
    size_t off = 0;
    auto alloc = [&](size_t bytes) -> void* {
        void* p = ws + off;
        off += (bytes + 255) & ~(size_t)255;
        return p;
    };
    short* WqT = (short*)alloc((size_t)128 * 512 * 2);
    short* WkT = (short*)alloc((size_t)128 * 512 * 2);
    short* WvT = (short*)alloc((size_t)512 * 512 * 2);
    short* W1T = (short*)alloc((size_t)1024 * 512 * 2);
    short* W2T = (short*)alloc((size_t)512 * 1024 * 2);
    short* qb  = (short*)alloc((size_t)16384 * 128 * 2);
    short* kbf = (short*)alloc((size_t)16384 * 128 * 2);
    short* vb  = (short*)alloc((size_t)16384 * 512 * 2);
    short* vT  = (short*)alloc((size_t)16384 * 512 * 2);
    short* hb  = (short*)alloc((size_t)16384 * 512 * 2);
    short* gb  = (short*)alloc((size_t)16384 * 1024 * 2);

    // weight transposes (f32 [K][N] -> bf16 [N][K])
    transpose_kernel<float><<<dim3(2, 8, 1),  256, 0, stream>>>(Wq, WqT, 512, 128, 0, 0);
    transpose_kernel<float><<<dim3(2, 8, 1),  256, 0, stream>>>(Wk, WkT, 512, 128, 0, 0);
    transpose_kernel<float><<<dim3(8, 8, 1),  256, 0, stream>>>(Wv, WvT, 512, 512, 0, 0);
    transpose_kernel<float><<<dim3(16, 8, 1), 256, 0, stream>>>(W1, W1T, 512, 1024, 0, 0);
    transpose_kernel<float><<<dim3(8, 16, 1), 256, 0, stream>>>(W2, W2T, 1024, 512, 0, 0);

    // projections: q = x Wq, k = y Wk, v = y Wv
    gemm_kernel<1, 0><<<dim3(128), 256, 0, stream>>>(x, WqT, qb,  nullptr, nullptr, 16384, 128, 512);
    gemm_kernel<1, 0><<<dim3(128), 256, 0, stream>>>(y, WkT, kbf, nullptr, nullptr, 16384, 128, 512);
    gemm_kernel<1, 0><<<dim3(512), 256, 0, stream>>>(y, WvT, vb,  nullptr, nullptr, 16384, 512, 512);

    // v -> v^T per batch: [2048][512] -> [512][2048]
    transpose_kernel<short><<<dim3(8, 32, 8), 256, 0, stream>>>(
        vb, vT, 2048, 512, (long long)2048 * 512, (long long)512 * 2048);

    // attention + residual -> d_out (x_res)
    flash_kernel<<<dim3(256), 512, 0, stream>>>(x, qb, kbf, vT, out);

    // layernorm -> hb
    ln_kernel<<<dim3(4096), 256, 0, stream>>>(out, gamma, beta, hb);

    // MLP
    gemm_kernel<0, 2><<<dim3(1024), 256, 0, stream>>>(hb, W1T, gb, b1, nullptr, 16384, 1024, 512);
    gemm_kernel<0, 3><<<dim3(512),  256, 0, stream>>>(gb, W2T, out, b2, out,    16384, 512, 1024);

    (void)in_sizes; (void)n_in; (void)out_size; (void)ws_size;
}